// Round 3
// baseline (2433.719 us; speedup 1.0000x reference)
//
#include <hip/hip_runtime.h>
#include <hip/hip_bf16.h>

// ---------------------------------------------------------------------------
// Grid attention v3, bf16 MFMA (gfx950). 4096 windows; n=49; D=512; 16h x 32.
// 512 threads = 8 waves = 4 pairs; pair p -> heads p*4..p*4+3.
// M-split: wave `sub` owns tokens sub*32..+31 for Q,K,V,softmax,PV.
//   -> q and P are wave-private (no barrier); only k,vt cross waves.
// x window held in VGPRs (32 bf16x8); k/vt double-buffered -> 1 barrier/head.
// ws layout (2.5MB): Wq/Wk/Wv pre-swizzled B-frags + biasD (same as v2).
// ---------------------------------------------------------------------------

typedef __bf16 bf16x8 __attribute__((ext_vector_type(8)));
typedef __attribute__((ext_vector_type(4))) float f32x4;

#define DEVI __device__ __forceinline__

DEVI unsigned short f2bf(float f) {
  union { float f; unsigned u; } v; v.f = f;
  unsigned r = v.u + 0x7FFFu + ((v.u >> 16) & 1u);
  return (unsigned short)(r >> 16);
}

#define MFMA16(a, b, c) __builtin_amdgcn_mfma_f32_16x16x32_bf16((a), (b), (c), 0, 0, 0)

#define SWZ_Y(r)  ((((unsigned)(r)) & 7u) << 4)
#define SWZ_QK(r) (((((unsigned)(r)) >> 1) & 3u) << 4)
#define SWZ_P(r)  (((((unsigned)(r)) >> 1) & 7u) << 4)
#define SWZ_VT(r) ((((unsigned)(r)) & 7u) << 4)

DEVI bf16x8 pack8(float4 a, float4 b) {
  union { unsigned u[4]; bf16x8 v; } r;
  r.u[0] = (unsigned)f2bf(a.x) | ((unsigned)f2bf(a.y) << 16);
  r.u[1] = (unsigned)f2bf(a.z) | ((unsigned)f2bf(a.w) << 16);
  r.u[2] = (unsigned)f2bf(b.x) | ((unsigned)f2bf(b.y) << 16);
  r.u[3] = (unsigned)f2bf(b.z) | ((unsigned)f2bf(b.w) << 16);
  return r.v;
}

// ---------------- prep: weights -> swizzled bf16 frags, bias -> D-layout ----
__global__ void prep_kernel(const float* __restrict__ Wq, const float* __restrict__ Wkv,
                            const float* __restrict__ bt, char* __restrict__ ws) {
  int t = blockIdx.x * 256 + threadIdx.x;
  if (t < 786432) {  // 3 * 16 * 2 * 16 * 64 * 8 bf16 elements
    int e = t & 7, lane = (t >> 3) & 63, ks = (t >> 9) & 15, nt = (t >> 13) & 1,
        h = (t >> 14) & 15, T = t >> 18;
    int row = ks * 32 + (lane >> 4) * 8 + e;     // K index in [0,512)
    int col = h * 32 + nt * 16 + (lane & 15);    // N index
    float v;
    if (T == 0)      v = Wq[row * 512 + col] * 0.17677669529663687f;  // fold 1/sqrt(32)
    else if (T == 1) v = Wkv[row * 1024 + col];
    else             v = Wkv[row * 1024 + 512 + col];
    ((unsigned short*)ws)[t] = f2bf(v);
  }
  if (t < 262144) {  // 16 * 4 * 4 * 64 * 4 f32
    int r = t & 3, lane = (t >> 2) & 63, nt = (t >> 8) & 3, mt = (t >> 10) & 3,
        h = (t >> 12) & 15;
    int i = mt * 16 + (lane >> 4) * 4 + r;
    int j = nt * 16 + (lane & 15);
    float v;
    if (j >= 49)      v = -1e30f;   // mask padded key columns
    else if (i >= 49) v = 0.0f;     // padded query rows: keep finite
    else {
      int hi = i / 7, wi = i % 7, hj = j / 7, wj = j % 7;
      v = bt[((hi - hj + 6) * 13 + (wi - wj + 6)) * 16 + h];
    }
    ((float*)(ws + 1572864))[t] = v;
  }
}

// ---------------- LDS loaders ------------------------------------------------
DEVI bf16x8 ldY(const char* base, int row, int kc) {
  unsigned a = ((unsigned)(row * 1024 + kc * 2)) ^ SWZ_Y(row);
  return *(const bf16x8*)(base + a);
}
DEVI bf16x8 ldQ(const char* base, int row, int kc) {
  unsigned a = ((unsigned)(row * 64 + kc * 2)) ^ SWZ_QK(row);
  return *(const bf16x8*)(base + a);
}
DEVI bf16x8 ldK(const char* base, int row, int kc) {
  int rc = row < 48 ? row : 48;   // clamp padded keys (bias -1e30 kills them)
  unsigned a = ((unsigned)(rc * 64 + kc * 2)) ^ SWZ_QK(rc);
  return *(const bf16x8*)(base + a);
}
DEVI bf16x8 ldP(const char* base, int ltok, int kc) {
  unsigned a = ((unsigned)(ltok * 128 + kc * 2)) ^ SWZ_P(ltok);
  return *(const bf16x8*)(base + a);
}
DEVI bf16x8 ldVT(const char* base, int dh, int kc) {
  unsigned a = ((unsigned)(dh * 128 + kc * 2)) ^ SWZ_VT(dh);
  return *(const bf16x8*)(base + a);
}

// ---------------- main fused kernel ----------------------------------------
__global__ __launch_bounds__(512, 2)
void attn_kernel(const float* __restrict__ x, const float* __restrict__ y,
                 const char* __restrict__ wsW, const float* __restrict__ biasD,
                 float* __restrict__ out) {
  extern __shared__ char smem[];
  char* yb = smem;                          // 50176
  const int tid = threadIdx.x;
  const int lane = tid & 63, wave = tid >> 6;
  const int p = wave >> 1, sub = wave & 1;
  const int g = lane >> 4, lr = lane & 15;
  char* pbase = smem + 50176 + p * 27008;   // per-pair block
  char* kbuf[2] = { pbase, pbase + 3136 };
  char* vtbuf[2] = { pbase + 6272, pbase + 10368 };
  char* qb = pbase + 14464;                 // 64 rows x 64B (halves wave-private)
  char* pbw = pbase + 18560 + sub * 4096;   //私 P: 32 rows x 128B
  float* sbw = (float*)(pbase + 26752 + sub * 128);  // 32 inv-sums (private)

  const int bw = blockIdx.x;
  const float* xs = x + (size_t)bw * 25088;
  const float* ys = y + (size_t)bw * 25088;

  // ---- stage y -> LDS bf16 ----
  for (int it = tid; it < 6272; it += 512) {
    float4 w = ((const float4*)ys)[it];
    int i = it >> 7;
    int kb2 = (it & 127) << 3;  // byte col
    unsigned a = ((unsigned)(i * 1024 + kb2)) ^ SWZ_Y(i);
    uint2 uy;
    uy.x = (unsigned)f2bf(w.x) | ((unsigned)f2bf(w.y) << 16);
    uy.y = (unsigned)f2bf(w.z) | ((unsigned)f2bf(w.w) << 16);
    *(uint2*)(yb + a) = uy;
  }

  // ---- x window A-frags -> registers (rows sub*32..+31, clamped) ----
  int rA0 = sub * 32 + lr;      if (rA0 > 48) rA0 = 48;
  int rA1 = sub * 32 + 16 + lr; if (rA1 > 48) rA1 = 48;
  bf16x8 xr0[16], xr1[16];
  #pragma unroll
  for (int ks = 0; ks < 16; ++ks) {
    const float* p0 = xs + rA0 * 512 + ks * 32 + g * 8;
    const float* p1 = xs + rA1 * 512 + ks * 32 + g * 8;
    float4 a0 = *(const float4*)p0, b0 = *(const float4*)(p0 + 4);
    float4 a1 = *(const float4*)p1, b1 = *(const float4*)(p1 + 4);
    xr0[ks] = pack8(a0, b0);
    xr1[ks] = pack8(a1, b1);
  }

  const bf16x8* wsQ = (const bf16x8*)wsW;
  const bf16x8* wsK = (const bf16x8*)(wsW + 524288);
  const bf16x8* wsV = (const bf16x8*)(wsW + 1048576);
  const f32x4* bD = (const f32x4*)biasD;
  const f32x4 fz = {0.f, 0.f, 0.f, 0.f};

  int rB0 = rA0, rB1 = rA1;  // same clamped rows for y

  // ---- projections for head h into (kb, vt) ----
  auto proj = [&](int h, char* kb, char* vt) {
    // Q = Xw @ Wq_h : rows sub*32..+31, all 32 dh
    f32x4 aq[2][2];
    aq[0][0] = fz; aq[0][1] = fz; aq[1][0] = fz; aq[1][1] = fz;
    {
      const bf16x8* pQ = wsQ + (size_t)(h * 2) * 1024;
      bf16x8 q0 = pQ[lane], q1 = pQ[1024 + lane];
      #pragma unroll
      for (int ks = 0; ks < 16; ++ks) {
        bf16x8 n0 = q0, n1 = q1;
        if (ks < 15) { n0 = pQ[(ks + 1) * 64 + lane]; n1 = pQ[1024 + (ks + 1) * 64 + lane]; }
        aq[0][0] = MFMA16(xr0[ks], q0, aq[0][0]);
        aq[1][0] = MFMA16(xr1[ks], q0, aq[1][0]);
        aq[0][1] = MFMA16(xr0[ks], q1, aq[0][1]);
        aq[1][1] = MFMA16(xr1[ks], q1, aq[1][1]);
        q0 = n0; q1 = n1;
      }
    }
    #pragma unroll
    for (int mt = 0; mt < 2; ++mt)
      #pragma unroll
      for (int nt = 0; nt < 2; ++nt) {
        int row0 = sub * 32 + mt * 16 + g * 4;
        int colb = (nt * 16 + lr) * 2;
        unsigned a0 = ((unsigned)(row0 * 64 + colb)) ^ SWZ_QK(row0);
        unsigned a2 = ((unsigned)((row0 + 2) * 64 + colb)) ^ SWZ_QK(row0 + 2);
        *(unsigned short*)(qb + a0)      = f2bf(aq[mt][nt][0]);
        *(unsigned short*)(qb + a0 + 64) = f2bf(aq[mt][nt][1]);
        *(unsigned short*)(qb + a2)      = f2bf(aq[mt][nt][2]);
        *(unsigned short*)(qb + a2 + 64) = f2bf(aq[mt][nt][3]);
      }

    // K,V = Yw @ Wk_h / Wv_h : rows sub*32..+31, all 32 dh (shared A-frags)
    f32x4 ak[2][2], av[2][2];
    ak[0][0] = fz; ak[0][1] = fz; ak[1][0] = fz; ak[1][1] = fz;
    av[0][0] = fz; av[0][1] = fz; av[1][0] = fz; av[1][1] = fz;
    {
      const bf16x8* pK = wsK + (size_t)(h * 2) * 1024;
      const bf16x8* pV = wsV + (size_t)(h * 2) * 1024;
      bf16x8 k0 = pK[lane], k1 = pK[1024 + lane];
      bf16x8 v0 = pV[lane], v1 = pV[1024 + lane];
      #pragma unroll
      for (int ks = 0; ks < 16; ++ks) {
        bf16x8 nk0 = k0, nk1 = k1, nv0 = v0, nv1 = v1;
        if (ks < 15) {
          nk0 = pK[(ks + 1) * 64 + lane]; nk1 = pK[1024 + (ks + 1) * 64 + lane];
          nv0 = pV[(ks + 1) * 64 + lane]; nv1 = pV[1024 + (ks + 1) * 64 + lane];
        }
        int kc = ks * 32 + g * 8;
        bf16x8 ya0 = ldY(yb, rB0, kc);
        bf16x8 ya1 = ldY(yb, rB1, kc);
        ak[0][0] = MFMA16(ya0, k0, ak[0][0]);
        ak[1][0] = MFMA16(ya1, k0, ak[1][0]);
        ak[0][1] = MFMA16(ya0, k1, ak[0][1]);
        ak[1][1] = MFMA16(ya1, k1, ak[1][1]);
        av[0][0] = MFMA16(ya0, v0, av[0][0]);
        av[1][0] = MFMA16(ya1, v0, av[1][0]);
        av[0][1] = MFMA16(ya0, v1, av[0][1]);
        av[1][1] = MFMA16(ya1, v1, av[1][1]);
        k0 = nk0; k1 = nk1; v0 = nv0; v1 = nv1;
      }
    }
    // store k (scatter u16, rows<49) and vt (packed uint2, all toks)
    #pragma unroll
    for (int mt = 0; mt < 2; ++mt)
      #pragma unroll
      for (int nt = 0; nt < 2; ++nt) {
        int row0 = sub * 32 + mt * 16 + g * 4;
        int dh = nt * 16 + lr;
        unsigned a0 = ((unsigned)(row0 * 64 + dh * 2)) ^ SWZ_QK(row0);
        unsigned a2 = ((unsigned)((row0 + 2) * 64 + dh * 2)) ^ SWZ_QK(row0 + 2);
        if (row0     < 49) *(unsigned short*)(kb + a0)      = f2bf(ak[mt][nt][0]);
        if (row0 + 1 < 49) *(unsigned short*)(kb + a0 + 64) = f2bf(ak[mt][nt][1]);
        if (row0 + 2 < 49) *(unsigned short*)(kb + a2)      = f2bf(ak[mt][nt][2]);
        if (row0 + 3 < 49) *(unsigned short*)(kb + a2 + 64) = f2bf(ak[mt][nt][3]);
        unsigned avad = ((unsigned)(dh * 128 + row0 * 2)) ^ SWZ_VT(dh);
        uint2 pk;
        pk.x = (unsigned)f2bf(av[mt][nt][0]) | ((unsigned)f2bf(av[mt][nt][1]) << 16);
        pk.y = (unsigned)f2bf(av[mt][nt][2]) | ((unsigned)f2bf(av[mt][nt][3]) << 16);
        *(uint2*)(vt + avad) = pk;
      }
  };

  // ---- attention for head h from (kb, vt) ----
  auto attn = [&](int h, const char* kb, const char* vt) {
    f32x4 bias[2][4];
    #pragma unroll
    for (int mi = 0; mi < 2; ++mi)
      #pragma unroll
      for (int nt = 0; nt < 4; ++nt)
        bias[mi][nt] = bD[(size_t)(((h * 4 + sub * 2 + mi) * 4 + nt) * 64 + lane)];

    bf16x8 qa0 = ldQ(qb, sub * 32 + lr, g * 8);
    bf16x8 qa1 = ldQ(qb, sub * 32 + 16 + lr, g * 8);
    bf16x8 kf[4];
    #pragma unroll
    for (int nt = 0; nt < 4; ++nt) kf[nt] = ldK(kb, nt * 16 + lr, g * 8);

    f32x4 sim[2][4];
    #pragma unroll
    for (int nt = 0; nt < 4; ++nt) {
      sim[0][nt] = MFMA16(qa0, kf[nt], fz);
      sim[1][nt] = MFMA16(qa1, kf[nt], fz);
    }

    // softmax rows (wave-private), write P + inv-sums
    #pragma unroll
    for (int mi = 0; mi < 2; ++mi) {
      f32x4 vals[4];
      #pragma unroll
      for (int nt = 0; nt < 4; ++nt) vals[nt] = sim[mi][nt] + bias[mi][nt];
      float inv[4];
      #pragma unroll
      for (int r = 0; r < 4; ++r) {
        float m = fmaxf(fmaxf(vals[0][r], vals[1][r]), fmaxf(vals[2][r], vals[3][r]));
        m = fmaxf(m, __shfl_xor(m, 1));
        m = fmaxf(m, __shfl_xor(m, 2));
        m = fmaxf(m, __shfl_xor(m, 4));
        m = fmaxf(m, __shfl_xor(m, 8));
        float s = 0.f;
        #pragma unroll
        for (int nt = 0; nt < 4; ++nt) {
          float pv = __expf(vals[nt][r] - m);
          vals[nt][r] = pv;
          s += pv;
        }
        s += __shfl_xor(s, 1);
        s += __shfl_xor(s, 2);
        s += __shfl_xor(s, 4);
        s += __shfl_xor(s, 8);
        inv[r] = 1.0f / s;
      }
      int lt0 = mi * 16 + g * 4;  // local token row
      #pragma unroll
      for (int nt = 0; nt < 4; ++nt) {
        unsigned cb = (unsigned)((nt * 16 + lr) * 2);
        unsigned a0 = ((unsigned)(lt0 * 128) + cb) ^ SWZ_P(lt0);
        unsigned a2 = ((unsigned)((lt0 + 2) * 128) + cb) ^ SWZ_P(lt0 + 2);
        *(unsigned short*)(pbw + a0)       = f2bf(vals[nt][0]);
        *(unsigned short*)(pbw + a0 + 128) = f2bf(vals[nt][1]);
        *(unsigned short*)(pbw + a2)       = f2bf(vals[nt][2]);
        *(unsigned short*)(pbw + a2 + 128) = f2bf(vals[nt][3]);
      }
      if (lr == 0) {
        sbw[lt0] = inv[0]; sbw[lt0 + 1] = inv[1];
        sbw[lt0 + 2] = inv[2]; sbw[lt0 + 3] = inv[3];
      }
    }

    // PV swapped: out^T[dh][tok] ; A = vt rows (shared), B = private P
    f32x4 acco[2][2];
    acco[0][0] = fz; acco[0][1] = fz; acco[1][0] = fz; acco[1][1] = fz;
    #pragma unroll
    for (int ks = 0; ks < 2; ++ks) {
      int jc = ks * 32 + g * 8;
      bf16x8 av0 = ldVT(vt, lr, jc);
      bf16x8 av1 = ldVT(vt, lr + 16, jc);
      bf16x8 bp0 = ldP(pbw, lr, jc);
      bf16x8 bp1 = ldP(pbw, 16 + lr, jc);
      acco[0][0] = MFMA16(av0, bp0, acco[0][0]);
      acco[0][1] = MFMA16(av0, bp1, acco[0][1]);
      acco[1][0] = MFMA16(av1, bp0, acco[1][0]);
      acco[1][1] = MFMA16(av1, bp1, acco[1][1]);
    }

    float* ow = out + (size_t)bw * 25088 + h * 32;
    #pragma unroll
    for (int nt = 0; nt < 2; ++nt) {
      int ltok = nt * 16 + lr;
      int tok = sub * 32 + ltok;
      if (tok < 49) {
        float inv = sbw[ltok];
        #pragma unroll
        for (int mt = 0; mt < 2; ++mt) {
          f32x4 vv = acco[mt][nt];
          vv[0] *= inv; vv[1] *= inv; vv[2] *= inv; vv[3] *= inv;
          *(f32x4*)(&ow[(size_t)tok * 512 + mt * 16 + g * 4]) = vv;
        }
      }
    }
  };

  // ---- pipeline: proj(0); [attn(i) || proj(i+1)] with 1 barrier/iter ----
  __syncthreads();                 // y staged
  proj(p * 4, kbuf[0], vtbuf[0]);
  __syncthreads();                 // k/vt[0] visible
  for (int hi = 0; hi < 4; ++hi) {
    const int h = p * 4 + hi;
    attn(h, kbuf[hi & 1], vtbuf[hi & 1]);
    if (hi < 3) {
      proj(h + 1, kbuf[(hi & 1) ^ 1], vtbuf[(hi & 1) ^ 1]);
      __syncthreads();             // next buffers visible; prev reads done
    }
  }
}

extern "C" void kernel_launch(void* const* d_in, const int* in_sizes, int n_in,
                              void* d_out, int out_size, void* d_ws, size_t ws_size,
                              hipStream_t stream) {
  (void)in_sizes; (void)n_in; (void)out_size; (void)ws_size;
  const float* x = (const float*)d_in[0];
  const float* y = (const float*)d_in[1];
  const float* Wq = (const float*)d_in[2];
  const float* Wkv = (const float*)d_in[3];
  const float* bt = (const float*)d_in[4];
  float* out = (float*)d_out;
  char* ws = (char*)d_ws;

  prep_kernel<<<3072, 256, 0, stream>>>(Wq, Wkv, bt, ws);

  (void)hipFuncSetAttribute((const void*)attn_kernel,
                            hipFuncAttributeMaxDynamicSharedMemorySize, 158208);
  attn_kernel<<<4096, 512, 158208, stream>>>(x, y, (const char*)ws,
                                             (const float*)(ws + 1572864), out);
}

// Round 5
// 1871.694 us; speedup vs baseline: 1.3003x; 1.3003x over previous
//
#include <hip/hip_runtime.h>

// ---------------------------------------------------------------------------
// Grid attention v4b, bf16 MFMA (gfx950). 4096 windows; n=49; D=512; 16h x 32.
// 512 threads = 8 waves; wave w owns heads {2w, 2w+1} END-TO-END.
// ONE __syncthreads (after y staging). All per-head state wave-private in LDS
// (q-transpose/vt aliased, P/kb aliased); intra-wave DS ordering via
// s_waitcnt lgkmcnt(0). Q's A-frags read straight from global x (L2-resident
// window) -- no x staging, no register blowout.
// ws layout (2.5MB): Wq/Wk/Wv pre-swizzled B-frags + biasD (as v2).
// ---------------------------------------------------------------------------

typedef __bf16 bf16x8 __attribute__((ext_vector_type(8)));
typedef __attribute__((ext_vector_type(4))) float f32x4;

#define DEVI __device__ __forceinline__

DEVI unsigned short f2bf(float f) {  // round-to-nearest-even
  union { float f; unsigned u; } v; v.f = f;
  unsigned r = v.u + 0x7FFFu + ((v.u >> 16) & 1u);
  return (unsigned short)(r >> 16);
}
DEVI unsigned pkbf(float a, float b) {
  return (unsigned)f2bf(a) | ((unsigned)f2bf(b) << 16);
}
DEVI bf16x8 pack8v(float4 a, float4 b) {
  union { unsigned u[4]; bf16x8 v; } r;
  r.u[0] = pkbf(a.x, a.y); r.u[1] = pkbf(a.z, a.w);
  r.u[2] = pkbf(b.x, b.y); r.u[3] = pkbf(b.z, b.w);
  return r.v;
}

#define MFMA16(a, b, c) __builtin_amdgcn_mfma_f32_16x16x32_bf16((a), (b), (c), 0, 0, 0)
#define WAVE_DS_FENCE() asm volatile("s_waitcnt lgkmcnt(0)" ::: "memory")

#define SWZ_Y(r)  ((((unsigned)(r)) & 7u) << 4)
#define SWZ_QK(r) (((((unsigned)(r)) >> 1) & 3u) << 4)
#define SWZ_P(r)  (((((unsigned)(r)) >> 1) & 7u) << 4)
#define SWZ_VT(r) ((((unsigned)(r)) & 7u) << 4)

// ---------------- prep: weights -> swizzled bf16 frags, bias -> D-layout ----
__global__ void prep_kernel(const float* __restrict__ Wq, const float* __restrict__ Wkv,
                            const float* __restrict__ bt, char* __restrict__ ws) {
  int t = blockIdx.x * 256 + threadIdx.x;
  if (t < 786432) {  // 3 * 16 * 2 * 16 * 64 * 8 bf16 elements
    int e = t & 7, lane = (t >> 3) & 63, ks = (t >> 9) & 15, nt = (t >> 13) & 1,
        h = (t >> 14) & 15, T = t >> 18;
    int row = ks * 32 + (lane >> 4) * 8 + e;     // K index in [0,512)
    int col = h * 32 + nt * 16 + (lane & 15);    // N index
    float v;
    if (T == 0)      v = Wq[row * 512 + col] * 0.17677669529663687f;  // fold 1/sqrt(32)
    else if (T == 1) v = Wkv[row * 1024 + col];
    else             v = Wkv[row * 1024 + 512 + col];
    ((unsigned short*)ws)[t] = f2bf(v);
  }
  if (t < 262144) {  // 16 * 4 * 4 * 64 * 4 f32
    int r = t & 3, lane = (t >> 2) & 63, nt = (t >> 8) & 3, mt = (t >> 10) & 3,
        h = (t >> 12) & 15;
    int i = mt * 16 + (lane >> 4) * 4 + r;
    int j = nt * 16 + (lane & 15);
    float v;
    if (j >= 49)      v = -1e30f;   // mask padded key columns
    else if (i >= 49) v = 0.0f;     // padded query rows: keep finite
    else {
      int hi = i / 7, wi = i % 7, hj = j / 7, wj = j % 7;
      v = bt[((hi - hj + 6) * 13 + (wi - wj + 6)) * 16 + h];
    }
    ((float*)(ws + 1572864))[t] = v;
  }
}

// ---------------- LDS loaders ------------------------------------------------
DEVI bf16x8 ldY(const char* base, int row, int kc) {
  unsigned a = ((unsigned)(row * 1024 + kc * 2)) ^ SWZ_Y(row);
  return *(const bf16x8*)(base + a);
}
DEVI bf16x8 ldA(const char* base, int row, int kc) {  // q/k frag (row pre-clamped)
  unsigned a = ((unsigned)(row * 64 + kc * 2)) ^ SWZ_QK(row);
  return *(const bf16x8*)(base + a);
}
DEVI bf16x8 ldP(const char* base, int row, int jc) {  // row pre-clamped
  unsigned a = ((unsigned)(row * 128 + jc * 2)) ^ SWZ_P(row);
  return *(const bf16x8*)(base + a);
}
DEVI bf16x8 ldVT(const char* base, int dh, int jc) {
  unsigned a = ((unsigned)(dh * 128 + jc * 2)) ^ SWZ_VT(dh);
  return *(const bf16x8*)(base + a);
}

// ---------------- main fused kernel ----------------------------------------
__global__ __launch_bounds__(512, 2)
void attn_kernel(const float* __restrict__ x, const float* __restrict__ y,
                 const char* __restrict__ wsW, const float* __restrict__ biasD,
                 float* __restrict__ out) {
  extern __shared__ char smem[];
  char* yb = smem;                           // 50176
  const int tid = threadIdx.x;
  const int lane = tid & 63, wave = tid >> 6;
  const int g = lane >> 4, lr = lane & 15;
  char* wb = smem + 50176 + wave * 10624;    // wave-PRIVATE scratch
  char* qt = wb;                             // 3136 (q transpose)
  char* vt = wb;                             // 4096 (aliases qt; written later)
  char* kb = wb + 4096;                      // 3136
  char* pb = wb + 4096;                      // 6272 (aliases kb; written later)
  float* sb = (float*)(wb + 10368);          // 49 inv-sums

  const int bw = blockIdx.x;
  const float* xs = x + (size_t)bw * 25088;
  const float* ys = y + (size_t)bw * 25088;

  // ---- stage y -> LDS bf16 (only staging; only barrier) ----
  for (int it = tid; it < 6272; it += 512) {
    float4 w4 = ((const float4*)ys)[it];
    int i = it >> 7;
    int kcb = (it & 127) << 3;
    unsigned a = ((unsigned)(i * 1024 + kcb)) ^ SWZ_Y(i);
    uint2 uy; uy.x = pkbf(w4.x, w4.y); uy.y = pkbf(w4.z, w4.w);
    *(uint2*)(yb + a) = uy;
  }
  __syncthreads();

  const bf16x8* wsQ = (const bf16x8*)wsW;
  const bf16x8* wsK = (const bf16x8*)(wsW + 524288);
  const bf16x8* wsV = (const bf16x8*)(wsW + 1048576);
  const f32x4* bD = (const f32x4*)biasD;
  const f32x4 fz = {0.f, 0.f, 0.f, 0.f};

  int rowm[4];  // clamped token row per m/n tile for frag reads
  #pragma unroll
  for (int mt = 0; mt < 4; ++mt) { int r = mt * 16 + lr; rowm[mt] = r > 48 ? 48 : r; }

  for (int hh = 0; hh < 2; ++hh) {
    const int h = wave * 2 + hh;
    WAVE_DS_FENCE();  // prev head's LDS reads done before qt overwrite

    // ---------- Q projection (A-frags straight from global x) ----------
    f32x4 aq[4][2];
    #pragma unroll
    for (int mt = 0; mt < 4; ++mt) { aq[mt][0] = fz; aq[mt][1] = fz; }
    {
      const bf16x8* pQ = wsQ + (size_t)(h * 2) * 1024 + lane;
      bf16x8 q0 = pQ[0], q1 = pQ[1024];
      float4 xf[2][4][2];
      #pragma unroll
      for (int mt = 0; mt < 4; ++mt) {
        const float* px = xs + rowm[mt] * 512 + g * 8;
        xf[0][mt][0] = *(const float4*)px; xf[0][mt][1] = *(const float4*)(px + 4);
      }
      #pragma unroll
      for (int ks = 0; ks < 16; ++ks) {
        if (ks < 15) {  // double-buffered next-ks loads (static idx: full unroll)
          #pragma unroll
          for (int mt = 0; mt < 4; ++mt) {
            const float* px = xs + rowm[mt] * 512 + (ks + 1) * 32 + g * 8;
            xf[(ks + 1) & 1][mt][0] = *(const float4*)px;
            xf[(ks + 1) & 1][mt][1] = *(const float4*)(px + 4);
          }
        }
        bf16x8 q0n = q0, q1n = q1;
        if (ks < 15) { int o = (ks + 1) * 64; q0n = pQ[o]; q1n = pQ[1024 + o]; }
        #pragma unroll
        for (int mt = 0; mt < 4; ++mt) {
          bf16x8 xa = pack8v(xf[ks & 1][mt][0], xf[ks & 1][mt][1]);
          aq[mt][0] = MFMA16(xa, q0, aq[mt][0]);
          aq[mt][1] = MFMA16(xa, q1, aq[mt][1]);
        }
        q0 = q0n; q1 = q1n;
      }
    }
    // q D-layout -> qt [row][dh]
    #pragma unroll
    for (int mt = 0; mt < 4; ++mt) {
      int row0 = mt * 16 + g * 4;
      #pragma unroll
      for (int nt = 0; nt < 2; ++nt) {
        unsigned cb = (unsigned)((nt * 16 + lr) * 2);
        unsigned a0 = ((unsigned)(row0 * 64) + cb) ^ SWZ_QK(row0);
        unsigned a2 = ((unsigned)((row0 + 2) * 64) + cb) ^ SWZ_QK(row0 + 2);
        if (row0     < 49) *(unsigned short*)(qt + a0)      = f2bf(aq[mt][nt][0]);
        if (row0 + 1 < 49) *(unsigned short*)(qt + a0 + 64) = f2bf(aq[mt][nt][1]);
        if (row0 + 2 < 49) *(unsigned short*)(qt + a2)      = f2bf(aq[mt][nt][2]);
        if (row0 + 3 < 49) *(unsigned short*)(qt + a2 + 64) = f2bf(aq[mt][nt][3]);
      }
    }
    WAVE_DS_FENCE();
    bf16x8 qa[4];
    #pragma unroll
    for (int mt = 0; mt < 4; ++mt) qa[mt] = ldA(qt, rowm[mt], g * 8);
    WAVE_DS_FENCE();  // qa in regs before vt overwrites qt

    // ---------- K,V projection (A-frags from yb LDS) ----------
    f32x4 ak[4][2], av4[4][2];
    #pragma unroll
    for (int mt = 0; mt < 4; ++mt) {
      ak[mt][0] = fz; ak[mt][1] = fz; av4[mt][0] = fz; av4[mt][1] = fz;
    }
    {
      const bf16x8* pK = wsK + (size_t)(h * 2) * 1024 + lane;
      const bf16x8* pV = wsV + (size_t)(h * 2) * 1024 + lane;
      bf16x8 k0 = pK[0], k1 = pK[1024], v0 = pV[0], v1 = pV[1024];
      #pragma unroll
      for (int ks = 0; ks < 16; ++ks) {
        int kc = ks * 32 + g * 8;
        bf16x8 ya[4];
        #pragma unroll
        for (int mt = 0; mt < 4; ++mt) ya[mt] = ldY(yb, rowm[mt], kc);
        bf16x8 k0n = k0, k1n = k1, v0n = v0, v1n = v1;
        if (ks < 15) {
          int o = (ks + 1) * 64;
          k0n = pK[o]; k1n = pK[1024 + o]; v0n = pV[o]; v1n = pV[1024 + o];
        }
        #pragma unroll
        for (int mt = 0; mt < 4; ++mt) {
          ak[mt][0]  = MFMA16(ya[mt], k0, ak[mt][0]);
          ak[mt][1]  = MFMA16(ya[mt], k1, ak[mt][1]);
          av4[mt][0] = MFMA16(ya[mt], v0, av4[mt][0]);
          av4[mt][1] = MFMA16(ya[mt], v1, av4[mt][1]);
        }
        k0 = k0n; k1 = k1n; v0 = v0n; v1 = v1n;
      }
    }
    // store k ([row][dh] scatter) + vt ([dh][tok] packed, all 64 toks)
    #pragma unroll
    for (int mt = 0; mt < 4; ++mt) {
      int row0 = mt * 16 + g * 4;
      #pragma unroll
      for (int nt = 0; nt < 2; ++nt) {
        int dh = nt * 16 + lr;
        unsigned cb = (unsigned)(dh * 2);
        unsigned a0 = ((unsigned)(row0 * 64) + cb) ^ SWZ_QK(row0);
        unsigned a2 = ((unsigned)((row0 + 2) * 64) + cb) ^ SWZ_QK(row0 + 2);
        if (row0     < 49) *(unsigned short*)(kb + a0)      = f2bf(ak[mt][nt][0]);
        if (row0 + 1 < 49) *(unsigned short*)(kb + a0 + 64) = f2bf(ak[mt][nt][1]);
        if (row0 + 2 < 49) *(unsigned short*)(kb + a2)      = f2bf(ak[mt][nt][2]);
        if (row0 + 3 < 49) *(unsigned short*)(kb + a2 + 64) = f2bf(ak[mt][nt][3]);
        unsigned avad = ((unsigned)(dh * 128 + row0 * 2)) ^ SWZ_VT(dh);
        uint2 pk2;
        pk2.x = pkbf(av4[mt][nt][0], av4[mt][nt][1]);
        pk2.y = pkbf(av4[mt][nt][2], av4[mt][nt][3]);
        *(uint2*)(vt + avad) = pk2;
      }
    }
    WAVE_DS_FENCE();

    // ---------- sim = q k^T + bias, softmax ----------
    bf16x8 kf[4];
    #pragma unroll
    for (int nt = 0; nt < 4; ++nt) kf[nt] = ldA(kb, rowm[nt], g * 8);
    f32x4 sim[4][4];
    #pragma unroll
    for (int mt = 0; mt < 4; ++mt)
      #pragma unroll
      for (int nt = 0; nt < 4; ++nt)
        sim[mt][nt] = MFMA16(qa[mt], kf[nt], fz);
    WAVE_DS_FENCE();  // kf in regs before pb overwrites kb

    #pragma unroll
    for (int mt = 0; mt < 4; ++mt) {
      f32x4 vals[4];
      #pragma unroll
      for (int nt = 0; nt < 4; ++nt)
        vals[nt] = sim[mt][nt] + bD[(size_t)(((h * 4 + mt) * 4 + nt) * 64 + lane)];
      float inv[4];
      #pragma unroll
      for (int r = 0; r < 4; ++r) {
        float m = fmaxf(fmaxf(vals[0][r], vals[1][r]), fmaxf(vals[2][r], vals[3][r]));
        m = fmaxf(m, __shfl_xor(m, 1));
        m = fmaxf(m, __shfl_xor(m, 2));
        m = fmaxf(m, __shfl_xor(m, 4));
        m = fmaxf(m, __shfl_xor(m, 8));
        float s = 0.f;
        #pragma unroll
        for (int nt = 0; nt < 4; ++nt) {
          float pv = __expf(vals[nt][r] - m);
          vals[nt][r] = pv;
          s += pv;
        }
        s += __shfl_xor(s, 1);
        s += __shfl_xor(s, 2);
        s += __shfl_xor(s, 4);
        s += __shfl_xor(s, 8);
        inv[r] = 1.0f / s;
      }
      int row0 = mt * 16 + g * 4;
      #pragma unroll
      for (int nt = 0; nt < 4; ++nt) {
        unsigned cb = (unsigned)((nt * 16 + lr) * 2);
        unsigned a0 = ((unsigned)(row0 * 128) + cb) ^ SWZ_P(row0);
        unsigned a2 = ((unsigned)((row0 + 2) * 128) + cb) ^ SWZ_P(row0 + 2);
        if (row0     < 49) *(unsigned short*)(pb + a0)       = f2bf(vals[nt][0]);
        if (row0 + 1 < 49) *(unsigned short*)(pb + a0 + 128) = f2bf(vals[nt][1]);
        if (row0 + 2 < 49) *(unsigned short*)(pb + a2)       = f2bf(vals[nt][2]);
        if (row0 + 3 < 49) *(unsigned short*)(pb + a2 + 128) = f2bf(vals[nt][3]);
      }
      if (lr == 0) {
        #pragma unroll
        for (int r = 0; r < 4; ++r) if (row0 + r < 49) sb[row0 + r] = inv[r];
      }
    }
    WAVE_DS_FENCE();  // P, sums visible (same wave)

    // ---------- PV swapped: out^T[dh][tok] = vt @ P ----------
    f32x4 acco[2][4];
    #pragma unroll
    for (int nt = 0; nt < 4; ++nt) { acco[0][nt] = fz; acco[1][nt] = fz; }
    #pragma unroll
    for (int js = 0; js < 2; ++js) {
      int jc = js * 32 + g * 8;
      bf16x8 a0v = ldVT(vt, lr, jc);
      bf16x8 a1v = ldVT(vt, lr + 16, jc);
      bf16x8 bp[4];
      #pragma unroll
      for (int nt = 0; nt < 4; ++nt) bp[nt] = ldP(pb, rowm[nt], jc);
      #pragma unroll
      for (int nt = 0; nt < 4; ++nt) {
        acco[0][nt] = MFMA16(a0v, bp[nt], acco[0][nt]);
        acco[1][nt] = MFMA16(a1v, bp[nt], acco[1][nt]);
      }
    }

    // ---------- normalize + store ----------
    float* ow = out + (size_t)bw * 25088 + h * 32;
    #pragma unroll
    for (int nt = 0; nt < 4; ++nt) {
      int tok = nt * 16 + lr;
      if (tok < 49) {
        float inv = sb[tok];
        #pragma unroll
        for (int mtd = 0; mtd < 2; ++mtd) {
          f32x4 vv = acco[mtd][nt];
          vv[0] *= inv; vv[1] *= inv; vv[2] *= inv; vv[3] *= inv;
          *(f32x4*)(&ow[(size_t)tok * 512 + mtd * 16 + g * 4]) = vv;
        }
      }
    }
  }
}

extern "C" void kernel_launch(void* const* d_in, const int* in_sizes, int n_in,
                              void* d_out, int out_size, void* d_ws, size_t ws_size,
                              hipStream_t stream) {
  (void)in_sizes; (void)n_in; (void)out_size; (void)ws_size;
  const float* x = (const float*)d_in[0];
  const float* y = (const float*)d_in[1];
  const float* Wq = (const float*)d_in[2];
  const float* Wkv = (const float*)d_in[3];
  const float* bt = (const float*)d_in[4];
  float* out = (float*)d_out;
  char* ws = (char*)d_ws;

  prep_kernel<<<3072, 256, 0, stream>>>(Wq, Wkv, bt, ws);

  (void)hipFuncSetAttribute((const void*)attn_kernel,
                            hipFuncAttributeMaxDynamicSharedMemorySize, 135168);
  attn_kernel<<<4096, 512, 135168, stream>>>(x, y, (const char*)ws,
                                             (const float*)(ws + 1572864), out);
}

// Round 6
// 792.588 us; speedup vs baseline: 3.0706x; 2.3615x over previous
//
#include <hip/hip_runtime.h>

// ---------------------------------------------------------------------------
// Grid attention v6, bf16 MFMA (gfx950). 4096 windows; n=49; D=512; 16h x 32.
// = v2 (932us baseline: x,y LDS-staged once, 4 wave-pairs, N-split proj /
//   M-split attention, 3 barriers/head) + deep weight-stream preloads:
//   Q-pass preloads all 16 B-frags; KV-pass rolls an 8-deep dual-stream
//   (k,v) preload; bias preloaded into regs before QK.
// ws layout (2.5MB): Wq/Wk/Wv pre-swizzled B-frags + biasD (same as v2).
// ---------------------------------------------------------------------------

typedef __bf16 bf16x8 __attribute__((ext_vector_type(8)));
typedef __attribute__((ext_vector_type(4))) float f32x4;

#define DEVI __device__ __forceinline__

DEVI unsigned short f2bf(float f) {  // round-to-nearest-even
  union { float f; unsigned u; } v; v.f = f;
  unsigned r = v.u + 0x7FFFu + ((v.u >> 16) & 1u);
  return (unsigned short)(r >> 16);
}

#define MFMA16(a, b, c) __builtin_amdgcn_mfma_f32_16x16x32_bf16((a), (b), (c), 0, 0, 0)

// ---------------- prep: weights -> swizzled bf16 frags, bias -> D-layout ----
__global__ void prep_kernel(const float* __restrict__ Wq, const float* __restrict__ Wkv,
                            const float* __restrict__ bt, char* __restrict__ ws) {
  int t = blockIdx.x * 256 + threadIdx.x;
  if (t < 786432) {  // 3 * 16 * 2 * 16 * 64 * 8 bf16 elements
    int e = t & 7, lane = (t >> 3) & 63, ks = (t >> 9) & 15, nt = (t >> 13) & 1,
        h = (t >> 14) & 15, T = t >> 18;
    int row = ks * 32 + (lane >> 4) * 8 + e;     // K index in [0,512)
    int col = h * 32 + nt * 16 + (lane & 15);    // N index
    float v;
    if (T == 0)      v = Wq[row * 512 + col] * 0.17677669529663687f;  // fold 1/sqrt(32)
    else if (T == 1) v = Wkv[row * 1024 + col];
    else             v = Wkv[row * 1024 + 512 + col];
    ((unsigned short*)ws)[t] = f2bf(v);
  }
  if (t < 262144) {  // 16 * 4 * 4 * 64 * 4 f32
    int r = t & 3, lane = (t >> 2) & 63, nt = (t >> 8) & 3, mt = (t >> 10) & 3,
        h = (t >> 12) & 15;
    int i = mt * 16 + (lane >> 4) * 4 + r;
    int j = nt * 16 + (lane & 15);
    float v;
    if (j >= 49)      v = -1e30f;   // mask padded key columns
    else if (i >= 49) v = 0.0f;     // padded query rows: keep finite
    else {
      int hi = i / 7, wi = i % 7, hj = j / 7, wj = j % 7;
      v = bt[((hi - hj + 6) * 13 + (wi - wj + 6)) * 16 + h];
    }
    ((float*)(ws + 1572864))[t] = v;
  }
}

// ---------------- LDS fragment loaders (XOR-swizzled) -----------------------
// xb/yb: [49][512] bf16, row stride 1024B, swz bits 4-6
DEVI bf16x8 ldXY(const char* base, int row, int kc) {
  unsigned a = ((unsigned)(row * 1024 + kc * 2)) ^ (((unsigned)row & 7u) << 4);
  return *(const bf16x8*)(base + a);
}
DEVI bf16x8 ldXY_c(const char* base, int row, int kc) {
  int rc = row < 48 ? row : 48;
  bf16x8 v = ldXY(base, rc, kc);
  if (row > 48) {
    union { long long z[2]; bf16x8 v; } u; u.z[0] = 0; u.z[1] = 0;
    v = u.v;
  }
  return v;
}
// qb/kb: [49][32] bf16, row stride 64B, swz bits 4-5
DEVI bf16x8 ldQK(const char* base, int row, int kc) {
  int rc = row < 48 ? row : 48;
  unsigned a = ((unsigned)(rc * 64 + kc * 2)) ^ (((unsigned)rc & 3u) << 4);
  return *(const bf16x8*)(base + a);
}
// pb: [49][64] bf16, row stride 128B, swz bits 4-6
DEVI bf16x8 ldP(const char* base, int row, int kc) {
  int rc = row < 48 ? row : 48;
  unsigned a = ((unsigned)(rc * 128 + kc * 2)) ^ (((unsigned)rc & 7u) << 4);
  return *(const bf16x8*)(base + a);
}
// vt: [32][64] bf16 (V transposed: [dh][tok]), row stride 128B, swz bits 4-6
DEVI bf16x8 ldVT(const char* base, int dh, int kc) {
  unsigned a = ((unsigned)(dh * 128 + kc * 2)) ^ (((unsigned)dh & 7u) << 4);
  return *(const bf16x8*)(base + a);
}

// ---------------- main fused kernel ----------------------------------------
__global__ __launch_bounds__(512, 2)
void attn_kernel(const float* __restrict__ x, const float* __restrict__ y,
                 const char* __restrict__ wsW, const float* __restrict__ biasD,
                 float* __restrict__ out) {
  extern __shared__ char smem[];
  char* xb = smem;            // 50176
  char* yb = smem + 50176;    // 50176
  const int tid = threadIdx.x;
  const int lane = tid & 63, wave = tid >> 6;
  const int p = wave >> 1, sub = wave & 1;
  const int g = lane >> 4, lr = lane & 15;
  char* wb = smem + 100352 + p * 10624;  // per-PAIR scratch
  char* qb = wb;              // 3136
  char* kb = wb + 3136;       // 3136
  char* vt = wb + 6272;       // 4096
  char* pb = wb;              // P aliases qb+kb (6272 bytes) -- barrier-guarded
  float* sb = (float*)(wb + 10368);  // 64 inv-sums

  const int bw = blockIdx.x;
  const float* xs = x + (size_t)bw * 25088;
  const float* ys = y + (size_t)bw * 25088;

  // ---- stage x,y windows to LDS as bf16 ----
  for (int it = tid; it < 6272; it += 512) {
    float4 v = ((const float4*)xs)[it];
    float4 w = ((const float4*)ys)[it];
    int i = it >> 7;               // row 0..48
    int k = (it & 127) << 2;       // col 0..508
    unsigned a = ((unsigned)(i * 1024 + k * 2)) ^ (((unsigned)i & 7u) << 4);
    uint2 ux, uy;
    ux.x = (unsigned)f2bf(v.x) | ((unsigned)f2bf(v.y) << 16);
    ux.y = (unsigned)f2bf(v.z) | ((unsigned)f2bf(v.w) << 16);
    uy.x = (unsigned)f2bf(w.x) | ((unsigned)f2bf(w.y) << 16);
    uy.y = (unsigned)f2bf(w.z) | ((unsigned)f2bf(w.w) << 16);
    *(uint2*)(xb + a) = ux;
    *(uint2*)(yb + a) = uy;
  }

  const bf16x8* wsQ = (const bf16x8*)wsW;
  const bf16x8* wsK = (const bf16x8*)(wsW + 524288);
  const bf16x8* wsV = (const bf16x8*)(wsW + 1048576);
  const f32x4* bD = (const f32x4*)biasD;
  const f32x4 fz = {0.f, 0.f, 0.f, 0.f};

  for (int hi = 0; hi < 4; ++hi) {
    const int h = p * 4 + hi;

    __syncthreads();  // scratch safe to rewrite (partner's PV of prev head done)

    // ---- Q = Xw @ Wq_h, N-split (cols sub*16..+16), 16-frag preload ----
    f32x4 accq[4];
    #pragma unroll
    for (int mt = 0; mt < 4; ++mt) accq[mt] = fz;
    {
      const bf16x8* pQ = wsQ + (size_t)((h * 2 + sub) * 16) * 64 + lane;
      bf16x8 bq[16];
      #pragma unroll
      for (int ks = 0; ks < 16; ++ks) bq[ks] = pQ[ks * 64];  // burst: full MLP
      #pragma unroll
      for (int ks = 0; ks < 16; ++ks) {
        int kc = ks * 32 + g * 8;
        accq[0] = MFMA16(ldXY(xb, lr, kc),        bq[ks], accq[0]);
        accq[1] = MFMA16(ldXY(xb, lr + 16, kc),   bq[ks], accq[1]);
        accq[2] = MFMA16(ldXY(xb, lr + 32, kc),   bq[ks], accq[2]);
        accq[3] = MFMA16(ldXY_c(xb, lr + 48, kc), bq[ks], accq[3]);
      }
    }
    // store q (D-layout -> [row][dh] bf16), dh = sub*16 + lr
    #pragma unroll
    for (int mt = 0; mt < 4; ++mt)
      #pragma unroll
      for (int r = 0; r < 4; ++r) {
        int row = mt * 16 + g * 4 + r;
        if (row < 49) {
          unsigned a = ((unsigned)(row * 64 + (sub * 16 + lr) * 2)) ^ (((unsigned)row & 3u) << 4);
          *(unsigned short*)(qb + a) = f2bf(accq[mt][r]);
        }
      }

    // ---- K,V = Yw @ Wk_h / Wv_h, N-split, rolling 8-deep dual preload ----
    f32x4 acck[4], accv[4];
    #pragma unroll
    for (int mt = 0; mt < 4; ++mt) { acck[mt] = fz; accv[mt] = fz; }
    {
      const bf16x8* pK = wsK + (size_t)((h * 2 + sub) * 16) * 64 + lane;
      const bf16x8* pV = wsV + (size_t)((h * 2 + sub) * 16) * 64 + lane;
      bf16x8 ksr[8], vsr[8];
      #pragma unroll
      for (int i = 0; i < 8; ++i) { ksr[i] = pK[i * 64]; vsr[i] = pV[i * 64]; }
      #pragma unroll
      for (int ks = 0; ks < 16; ++ks) {
        bf16x8 bk = ksr[ks & 7], bv = vsr[ks & 7];
        if (ks < 8) {  // refill consumed slot with frag ks+8 (static idx)
          ksr[ks & 7] = pK[(ks + 8) * 64];
          vsr[ks & 7] = pV[(ks + 8) * 64];
        }
        int kc = ks * 32 + g * 8;
        bf16x8 a0 = ldXY(yb, lr, kc);
        bf16x8 a1 = ldXY(yb, lr + 16, kc);
        bf16x8 a2 = ldXY(yb, lr + 32, kc);
        bf16x8 a3 = ldXY_c(yb, lr + 48, kc);
        acck[0] = MFMA16(a0, bk, acck[0]);
        acck[1] = MFMA16(a1, bk, acck[1]);
        acck[2] = MFMA16(a2, bk, acck[2]);
        acck[3] = MFMA16(a3, bk, acck[3]);
        accv[0] = MFMA16(a0, bv, accv[0]);
        accv[1] = MFMA16(a1, bv, accv[1]);
        accv[2] = MFMA16(a2, bv, accv[2]);
        accv[3] = MFMA16(a3, bv, accv[3]);
      }
    }
    // store k ([row][dh], scatter u16) and v transposed ([dh][tok], packed b64)
    #pragma unroll
    for (int mt = 0; mt < 4; ++mt) {
      #pragma unroll
      for (int r = 0; r < 4; ++r) {
        int row = mt * 16 + g * 4 + r;
        if (row < 49) {
          unsigned a = ((unsigned)(row * 64 + (sub * 16 + lr) * 2)) ^ (((unsigned)row & 3u) << 4);
          *(unsigned short*)(kb + a) = f2bf(acck[mt][r]);
        }
      }
      int dh = sub * 16 + lr;
      int t0 = mt * 16 + g * 4;
      unsigned av = ((unsigned)(dh * 128 + t0 * 2)) ^ (((unsigned)dh & 7u) << 4);
      uint2 pk;
      pk.x = (unsigned)f2bf(accv[mt][0]) | ((unsigned)f2bf(accv[mt][1]) << 16);
      pk.y = (unsigned)f2bf(accv[mt][2]) | ((unsigned)f2bf(accv[mt][3]) << 16);
      *(uint2*)(vt + av) = pk;
    }

    __syncthreads();  // q,k,v visible to both waves of the pair

    // ---- bias preload (hidden under QK) ----
    f32x4 bias[2][4];
    #pragma unroll
    for (int mi = 0; mi < 2; ++mi)
      #pragma unroll
      for (int nt = 0; nt < 4; ++nt)
        bias[mi][nt] = bD[(size_t)(((h * 4 + sub * 2 + mi) * 4 + nt) * 64 + lane)];

    // ---- sim = q @ k^T, M-split: this wave does rows sub*32..+32 ----
    bf16x8 qa[2], kf[4];
    #pragma unroll
    for (int mi = 0; mi < 2; ++mi) qa[mi] = ldQK(qb, sub * 32 + mi * 16 + lr, g * 8);
    #pragma unroll
    for (int nt = 0; nt < 4; ++nt) kf[nt] = ldQK(kb, nt * 16 + lr, g * 8);
    f32x4 accs[2][4];
    #pragma unroll
    for (int mi = 0; mi < 2; ++mi)
      #pragma unroll
      for (int nt = 0; nt < 4; ++nt)
        accs[mi][nt] = MFMA16(qa[mi], kf[nt], fz);

    // ---- bias + softmax (16-lane butterflies), rows sub*32..+32 ----
    float sinv[2][4];
    #pragma unroll
    for (int mi = 0; mi < 2; ++mi) {
      f32x4 vals[4];
      #pragma unroll
      for (int nt = 0; nt < 4; ++nt)
        vals[nt] = accs[mi][nt] + bias[mi][nt];
      #pragma unroll
      for (int r = 0; r < 4; ++r) {
        float m = fmaxf(fmaxf(vals[0][r], vals[1][r]), fmaxf(vals[2][r], vals[3][r]));
        m = fmaxf(m, __shfl_xor(m, 1));
        m = fmaxf(m, __shfl_xor(m, 2));
        m = fmaxf(m, __shfl_xor(m, 4));
        m = fmaxf(m, __shfl_xor(m, 8));
        float s = 0.f;
        #pragma unroll
        for (int nt = 0; nt < 4; ++nt) {
          float pv = __expf(vals[nt][r] - m);
          vals[nt][r] = pv;
          s += pv;
        }
        s += __shfl_xor(s, 1);
        s += __shfl_xor(s, 2);
        s += __shfl_xor(s, 4);
        s += __shfl_xor(s, 8);
        sinv[mi][r] = 1.0f / s;
      }
      accs[mi][0] = vals[0]; accs[mi][1] = vals[1];
      accs[mi][2] = vals[2]; accs[mi][3] = vals[3];
    }

    __syncthreads();  // both waves done reading qb/kb frags -> pb may overwrite

    // ---- write P (unnormalized) + inv-sums ----
    #pragma unroll
    for (int mi = 0; mi < 2; ++mi) {
      int mt_g = sub * 2 + mi;
      #pragma unroll
      for (int r = 0; r < 4; ++r) {
        int row = mt_g * 16 + g * 4 + r;
        if (row < 49) {
          #pragma unroll
          for (int nt = 0; nt < 4; ++nt) {
            unsigned a = ((unsigned)(row * 128 + (nt * 16 + lr) * 2)) ^ (((unsigned)row & 7u) << 4);
            *(unsigned short*)(pb + a) = f2bf(accs[mi][nt][r]);
          }
          if (lr == 0) sb[row] = sinv[mi][r];
        }
      }
    }

    // ---- PV, swapped operands: out^T[dh][tok] = V^T @ P^T-shaped ----
    f32x4 acco[2][2];
    acco[0][0] = fz; acco[0][1] = fz; acco[1][0] = fz; acco[1][1] = fz;
    #pragma unroll
    for (int ks = 0; ks < 2; ++ks) {
      int jc = ks * 32 + g * 8;
      bf16x8 av0 = ldVT(vt, lr, jc);
      bf16x8 av1 = ldVT(vt, lr + 16, jc);
      bf16x8 bp0 = ldP(pb, (sub * 2 + 0) * 16 + lr, jc);
      bf16x8 bp1 = ldP(pb, (sub * 2 + 1) * 16 + lr, jc);
      acco[0][0] = MFMA16(av0, bp0, acco[0][0]);
      acco[0][1] = MFMA16(av0, bp1, acco[0][1]);
      acco[1][0] = MFMA16(av1, bp0, acco[1][0]);
      acco[1][1] = MFMA16(av1, bp1, acco[1][1]);
    }

    // ---- normalize + store (float4, dh-contiguous) ----
    float* ow = out + (size_t)bw * 25088 + h * 32;
    #pragma unroll
    for (int ntl = 0; ntl < 2; ++ntl) {
      int tok = (sub * 2 + ntl) * 16 + lr;
      if (tok < 49) {
        float inv = sb[tok];
        #pragma unroll
        for (int mt = 0; mt < 2; ++mt) {
          f32x4 vv = acco[mt][ntl];
          vv[0] *= inv; vv[1] *= inv; vv[2] *= inv; vv[3] *= inv;
          *(f32x4*)(&ow[(size_t)tok * 512 + mt * 16 + g * 4]) = vv;
        }
      }
    }
  }
}

extern "C" void kernel_launch(void* const* d_in, const int* in_sizes, int n_in,
                              void* d_out, int out_size, void* d_ws, size_t ws_size,
                              hipStream_t stream) {
  (void)in_sizes; (void)n_in; (void)out_size; (void)ws_size;
  const float* x = (const float*)d_in[0];
  const float* y = (const float*)d_in[1];
  const float* Wq = (const float*)d_in[2];
  const float* Wkv = (const float*)d_in[3];
  const float* bt = (const float*)d_in[4];
  float* out = (float*)d_out;
  char* ws = (char*)d_ws;

  prep_kernel<<<3072, 256, 0, stream>>>(Wq, Wkv, bt, ws);

  (void)hipFuncSetAttribute((const void*)attn_kernel,
                            hipFuncAttributeMaxDynamicSharedMemorySize, 142848);
  attn_kernel<<<4096, 512, 142848, stream>>>(x, y, (const char*)ws,
                                             (const float*)(ws + 1572864), out);
}